// Round 5
// baseline (294.046 us; speedup 1.0000x reference)
//
#include <hip/hip_runtime.h>
#include <hip/hip_cooperative_groups.h>
#include <cstdint>

namespace cg = cooperative_groups;

#define NTOPK 13
#define FEPS 1e-9f
#define CAP 64        // per-(b,g) positive-key capacity (p ~ 3 here)
#define GSPLIT 4      // gt-dimension split of the scan phase
#define NBLOCKS 512   // 2 blocks/CU on 256 CUs -- always co-resident
#define NTHREADS 256

// ---------------------------------------------------------------------------
// metric[l] for one gt. Identical arithmetic to the reference.
// ---------------------------------------------------------------------------
__device__ __forceinline__ float tal_metric(int l, float4 gb, float ag,
                                            const float4* __restrict__ pb,
                                            const float* __restrict__ ps,
                                            const float2* __restrict__ apt,
                                            int C) {
    float2 a = apt[l];
    float dmin = fminf(fminf(a.x - gb.x, a.y - gb.y),
                       fminf(gb.z - a.x, gb.w - a.y));
    float m = 0.0f;
    if (dmin > FEPS) {
        float4 p = pb[l];
        float iw = fmaxf(fminf(gb.z, p.z) - fmaxf(gb.x, p.x), 0.0f);
        float ih = fmaxf(fminf(gb.w, p.w) - fmaxf(gb.y, p.y), 0.0f);
        float inter = iw * ih;
        float ap2 = (p.z - p.x) * (p.w - p.y);
        float iou = inter / (((ag + ap2) - inter) + 1e-9f);
        m = ps[(size_t)l * C] * powf(iou, 6.0f);
    }
    return m;
}

// ---------------------------------------------------------------------------
// One cooperative kernel, 5 phases separated by grid.sync():
//   0: zero cnt/max_m/max_i/maskbits
//   1: sparse scan -> per-(b,g) positive key lists (key = m_bits<<32 | ~l)
//   2: per-(b,g) top-13 selection (wave shfl) + zero-fill, sets maskbits
//   3: per-(b,l) assignment resolve, labels/bboxes out, per-gt max atomics
//   4: per-(b,l,c) score write (float4 or scalar)
// ---------------------------------------------------------------------------
__global__ __launch_bounds__(NTHREADS) void k_fused(
        const float* __restrict__ pred_scores,
        const float4* __restrict__ pred_bboxes,
        const float2* __restrict__ anchor_points,
        const int* __restrict__ gt_labels,
        const float4* __restrict__ gt_bboxes,
        const float* __restrict__ pad_gt_mask,
        const int* __restrict__ bg_ptr,
        uint32_t* __restrict__ zero_region,   // [cnt | max_m | max_i | maskbits]
        uint64_t* __restrict__ keys,
        int* __restrict__ assigned_g,
        float* __restrict__ align_val,
        float* __restrict__ out_labels,
        float4* __restrict__ out_bboxes,
        float* __restrict__ out_scores,
        int B, int L, int C, int n, int W) {
    cg::grid_group grid = cg::this_grid();
    extern __shared__ char smem[];
    float4* sbox = (float4*)smem;
    int*    slab = (int*)(sbox + n);

    uint32_t* cnt      = zero_region;
    uint32_t* max_m    = cnt + (size_t)B * n;
    uint32_t* max_i    = max_m + (size_t)B * n;
    uint32_t* maskbits = max_i + (size_t)B * n;

    const int t = threadIdx.x;
    const int lane = t & 63;
    const int TILES = (L + NTHREADS - 1) / NTHREADS;

    // ---- phase 0: zero workspace ----
    {
        size_t zn = (size_t)3 * B * n + (size_t)B * L * W;
        for (size_t i = (size_t)blockIdx.x * NTHREADS + t; i < zn;
             i += (size_t)gridDim.x * NTHREADS)
            zero_region[i] = 0;
    }
    grid.sync();

    // ---- phase 1: sparse scan ----
    {
        int per = (n + GSPLIT - 1) / GSPLIT;
        int V = TILES * B * GSPLIT;
        for (int v = blockIdx.x; v < V; v += gridDim.x) {
            int tile = v % TILES;
            int rem = v / TILES;
            int b = rem % B;
            int z = rem / B;
            int gbeg = z * per;
            int gend = min(n, gbeg + per);
            int ng = gend - gbeg;

            __syncthreads();  // protect LDS reuse across loop iterations
            for (int i = t; i < ng; i += NTHREADS) {
                int g = gbeg + i;
                float4 gb = gt_bboxes[(size_t)b * n + g];
                if (pad_gt_mask[(size_t)b * n + g] == 0.0f) {
                    gb.x = 1e30f; gb.y = 1e30f; gb.z = -1e30f; gb.w = -1e30f;
                }
                sbox[i] = gb;
                slab[i] = gt_labels[(size_t)b * n + g];
            }
            __syncthreads();

            int l = tile * NTHREADS + t;
            if (l < L) {
                float2 a = anchor_points[l];
                float4 p = pred_bboxes[(size_t)b * L + l];
                float ap = (p.z - p.x) * (p.w - p.y);
                const float* ps = pred_scores + ((size_t)b * L + l) * C;
                for (int i = 0; i < ng; ++i) {
                    float4 gb = sbox[i];
                    float dmin = fminf(fminf(a.x - gb.x, a.y - gb.y),
                                       fminf(gb.z - a.x, gb.w - a.y));
                    if (dmin > FEPS) {
                        float iw = fmaxf(fminf(gb.z, p.z) - fmaxf(gb.x, p.x), 0.0f);
                        float ih = fmaxf(fminf(gb.w, p.w) - fmaxf(gb.y, p.y), 0.0f);
                        float inter = iw * ih;
                        if (inter > 0.0f) {
                            float ag = (gb.z - gb.x) * (gb.w - gb.y);
                            float iou = inter / (((ag + ap) - inter) + 1e-9f);
                            float m = ps[slab[i]] * powf(iou, 6.0f);
                            if (m > 0.0f) {
                                int bg = b * n + gbeg + i;
                                uint32_t off = atomicAdd(&cnt[bg], 1u);
                                if (off < CAP)
                                    keys[(size_t)bg * CAP + off] =
                                        ((uint64_t)__float_as_uint(m) << 32) |
                                        (uint32_t)(~l);
                            }
                        }
                    }
                }
            }
        }
    }
    grid.sync();

    // ---- phase 2: selection, one wave per (b,g) ----
    {
        int gw = blockIdx.x * (NTHREADS / 64) + (t >> 6);
        int nw = gridDim.x * (NTHREADS / 64);
        for (int bg = gw; bg < B * n; bg += nw) {
            if (pad_gt_mask[bg] == 0.0f) continue;
            int b = bg / n;
            int g = bg - b * n;
            uint32_t p = cnt[bg];
            int mypick = -1;

            if (p <= CAP) {
                uint64_t mykey = (lane < (int)p) ? keys[(size_t)bg * CAP + lane] : 0ull;
                int np = min((int)p, NTOPK);
                for (int k = 0; k < np; ++k) {
                    uint64_t mk = mykey;
                    for (int s = 1; s < 64; s <<= 1) {
                        uint64_t o = __shfl_xor((unsigned long long)mk, s);
                        if (o > mk) mk = o;
                    }
                    if (lane == k) mypick = (int)~(uint32_t)mk;
                    if (mykey == mk) mykey = 0ull;  // unique owner removes
                }
                // zero-fill: lowest-index anchors not among the positive picks
                int fill = np, c = 0;
                while (fill < NTOPK) {
                    bool inP = __ballot(lane < np && mypick == c) != 0ull;
                    if (!inP) {
                        if (lane == fill) mypick = c;
                        ++fill;
                    }
                    ++c;
                }
            } else {
                // dense fallback (not taken for this data): 13 recompute rounds
                float4 gb = gt_bboxes[bg];
                float ag = (gb.z - gb.x) * (gb.w - gb.y);
                const float4* pb = pred_bboxes + (size_t)b * L;
                const float*  ps = pred_scores + ((size_t)b * L) * C + gt_labels[bg];
                for (int k = 0; k < NTOPK; ++k) {
                    uint64_t bk = 0;
                    for (int l = lane; l < L; l += 64) {
                        bool taken = false;
                        for (int j = 0; j < k; ++j)
                            taken |= (__shfl(mypick, j) == l);
                        if (taken) continue;
                        float m = tal_metric(l, gb, ag, pb, ps, anchor_points, C);
                        uint64_t key = ((uint64_t)__float_as_uint(m) << 32) |
                                       (uint32_t)(~l);
                        if (key > bk) bk = key;
                    }
                    for (int s = 1; s < 64; s <<= 1) {
                        uint64_t o = __shfl_xor((unsigned long long)bk, s);
                        if (o > bk) bk = o;
                    }
                    if (lane == k) mypick = (int)~(uint32_t)bk;
                }
            }

            if (lane < NTOPK) {
                int l = mypick;
                float4 gb = gt_bboxes[bg];
                float2 a = anchor_points[l];
                float dmin = fminf(fminf(a.x - gb.x, a.y - gb.y),
                                   fminf(gb.z - a.x, gb.w - a.y));
                if (dmin > FEPS) {
                    atomicOr(&maskbits[((size_t)b * L + l) * W + (g >> 5)],
                             1u << (g & 31));
                }
            }
        }
    }
    grid.sync();

    // ---- phase 3: assignment resolve ----
    {
        int V = TILES * B;
        for (int v = blockIdx.x; v < V; v += gridDim.x) {
            int tile = v % TILES;
            int b = v / TILES;
            __syncthreads();
            for (int i = t; i < n; i += NTHREADS) {
                sbox[i] = gt_bboxes[(size_t)b * n + i];  // raw (unmasked) boxes
                slab[i] = gt_labels[(size_t)b * n + i];
            }
            __syncthreads();

            int l = tile * NTHREADS + t;
            if (l < L) {
                size_t idx = (size_t)b * L + l;
                int sum = 0, firstg = -1;
                for (int w = 0; w < W; ++w) {
                    uint32_t bits = maskbits[idx * W + w];
                    if (bits && firstg < 0) firstg = w * 32 + __ffs(bits) - 1;
                    sum += __popc(bits);
                }

                float4 p = pred_bboxes[idx];
                float ap = (p.z - p.x) * (p.w - p.y);

                int g;
                if (sum == 0) g = -1;
                else if (sum == 1) g = firstg;
                else {
                    // is_max_iou: first-max argmax over ALL gts of raw IoU (LDS)
                    float best = -1.0f; int bi = 0;
                    for (int gg = 0; gg < n; ++gg) {
                        float4 gb = sbox[gg];
                        float iw = fmaxf(fminf(gb.z, p.z) - fmaxf(gb.x, p.x), 0.0f);
                        float ih = fmaxf(fminf(gb.w, p.w) - fmaxf(gb.y, p.y), 0.0f);
                        float inter = iw * ih;
                        float ag = (gb.z - gb.x) * (gb.w - gb.y);
                        float iou = inter / (((ag + ap) - inter) + 1e-9f);
                        if (iou > best) { best = iou; bi = gg; }
                    }
                    g = bi;
                }
                assigned_g[idx] = g;

                float av = 0.0f;
                if (g >= 0) {
                    float4 gb = sbox[g];
                    float iw = fmaxf(fminf(gb.z, p.z) - fmaxf(gb.x, p.x), 0.0f);
                    float ih = fmaxf(fminf(gb.w, p.w) - fmaxf(gb.y, p.y), 0.0f);
                    float inter = iw * ih;
                    float ag = (gb.z - gb.x) * (gb.w - gb.y);
                    float iou = inter / (((ag + ap) - inter) + 1e-9f);
                    int label = slab[g];
                    float score = pred_scores[idx * C + label];
                    av = score * powf(iou, 6.0f);
                    atomicMax(&max_m[(size_t)b * n + g], __float_as_uint(av));
                    atomicMax(&max_i[(size_t)b * n + g], __float_as_uint(iou));
                    out_labels[idx] = (float)label;
                    out_bboxes[idx] = gb;
                } else {
                    out_labels[idx] = (float)(*bg_ptr);
                    out_bboxes[idx] = sbox[0];  // agi==0 gather, unmasked
                }
                align_val[idx] = av;
            }
        }
    }
    grid.sync();

    // ---- phase 4: scores ----
    if ((C & 3) == 0) {
        int C4 = C >> 2;
        int total4 = B * L * C4;
        float4* out4 = (float4*)out_scores;
        for (int idx = blockIdx.x * NTHREADS + t; idx < total4;
             idx += gridDim.x * NTHREADS) {
            int c0 = (idx % C4) * 4;
            int bl = idx / C4;
            int g = assigned_g[bl];
            float4 v = make_float4(0.f, 0.f, 0.f, 0.f);
            if (g >= 0) {
                int b = bl / L;
                int label = gt_labels[(size_t)b * n + g];
                int bgi = *bg_ptr;
                float mm = __uint_as_float(max_m[(size_t)b * n + g]);
                float mi = __uint_as_float(max_i[(size_t)b * n + g]);
                float val = align_val[bl] / (mm + FEPS) * mi;
                int cls0 = (c0     < bgi) ? c0     : c0 + 1;
                int cls1 = (c0 + 1 < bgi) ? c0 + 1 : c0 + 2;
                int cls2 = (c0 + 2 < bgi) ? c0 + 2 : c0 + 3;
                int cls3 = (c0 + 3 < bgi) ? c0 + 3 : c0 + 4;
                if (cls0 == label) v.x = val;
                if (cls1 == label) v.y = val;
                if (cls2 == label) v.z = val;
                if (cls3 == label) v.w = val;
            }
            out4[idx] = v;
        }
    } else {
        int total = B * L * C;
        for (int idx = blockIdx.x * NTHREADS + t; idx < total;
             idx += gridDim.x * NTHREADS) {
            int c = idx % C;
            int bl = idx / C;
            int g = assigned_g[bl];
            float v = 0.0f;
            if (g >= 0) {
                int b = bl / L;
                int label = gt_labels[(size_t)b * n + g];
                int bgi = *bg_ptr;
                int cls = (c < bgi) ? c : c + 1;
                if (cls == label) {
                    float mm = __uint_as_float(max_m[(size_t)b * n + g]);
                    float mi = __uint_as_float(max_i[(size_t)b * n + g]);
                    v = align_val[bl] / (mm + FEPS) * mi;
                }
            }
            out_scores[idx] = v;
        }
    }
}

// ---------------------------------------------------------------------------
extern "C" void kernel_launch(void* const* d_in, const int* in_sizes, int n_in,
                              void* d_out, int out_size, void* d_ws, size_t ws_size,
                              hipStream_t stream) {
    const float*  pred_scores   = (const float*)d_in[0];
    const float4* pred_bboxes   = (const float4*)d_in[1];
    const float2* anchor_points = (const float2*)d_in[2];
    const int*    gt_labels     = (const int*)d_in[3];
    const float4* gt_bboxes     = (const float4*)d_in[4];
    const float*  pad_gt_mask   = (const float*)d_in[5];
    const int*    bg_ptr        = (const int*)d_in[6];

    int L = in_sizes[2] / 2;
    int B = in_sizes[1] / (L * 4);
    int C = in_sizes[0] / (B * L);
    int n = in_sizes[3] / B;
    int W = (n + 31) / 32;

    char* ws = (char*)d_ws;
    uint32_t* zero_region = (uint32_t*)ws;
    ws += ((size_t)3 * B * n + (size_t)B * L * W) * sizeof(uint32_t);
    uint64_t* keys = (uint64_t*)ws;       ws += (size_t)B * n * CAP * sizeof(uint64_t);
    int*      assigned_g = (int*)ws;      ws += (size_t)B * L * sizeof(int);
    float*    align_val  = (float*)ws;    ws += (size_t)B * L * sizeof(float);

    float*  out_labels = (float*)d_out;
    float4* out_bboxes = (float4*)((float*)d_out + (size_t)B * L);
    float*  out_scores = (float*)d_out + (size_t)B * L * 5;

    void* kargs[] = {
        (void*)&pred_scores, (void*)&pred_bboxes, (void*)&anchor_points,
        (void*)&gt_labels, (void*)&gt_bboxes, (void*)&pad_gt_mask,
        (void*)&bg_ptr, (void*)&zero_region, (void*)&keys,
        (void*)&assigned_g, (void*)&align_val,
        (void*)&out_labels, (void*)&out_bboxes, (void*)&out_scores,
        (void*)&B, (void*)&L, (void*)&C, (void*)&n, (void*)&W
    };
    size_t smem = (size_t)n * (sizeof(float4) + sizeof(int));
    hipLaunchCooperativeKernel((const void*)k_fused, dim3(NBLOCKS), dim3(NTHREADS),
                               kargs, (unsigned int)smem, stream);
}

// Round 6
// 55.166 us; speedup vs baseline: 5.3302x; 5.3302x over previous
//
#include <hip/hip_runtime.h>
#include <cstdint>

#define NTOPK 13
#define FEPS 1e-9f
#define CAP 64          // per-(b,g) positive-key capacity (p ~ 3 here)
#define GSPLIT 4        // gt-dimension split of the scan grid
#define MASKED_FLAG (1 << 30)

// ---------------------------------------------------------------------------
// metric[l] for one gt. Identical arithmetic to the reference.
// ---------------------------------------------------------------------------
__device__ __forceinline__ float tal_metric(int l, float4 gb, float ag,
                                            const float4* __restrict__ pb,
                                            const float* __restrict__ ps,
                                            const float2* __restrict__ apt,
                                            int C) {
    float2 a = apt[l];
    float dmin = fminf(fminf(a.x - gb.x, a.y - gb.y),
                       fminf(gb.z - a.x, gb.w - a.y));
    float m = 0.0f;
    if (dmin > FEPS) {
        float4 p = pb[l];
        float iw = fmaxf(fminf(gb.z, p.z) - fmaxf(gb.x, p.x), 0.0f);
        float ih = fmaxf(fminf(gb.w, p.w) - fmaxf(gb.y, p.y), 0.0f);
        float inter = iw * ih;
        float ap2 = (p.z - p.x) * (p.w - p.y);
        float iou = inter / (((ag + ap2) - inter) + 1e-9f);
        m = ps[(size_t)l * C] * powf(iou, 6.0f);
    }
    return m;
}

// ---------------------------------------------------------------------------
// Kernel 1: sparse scan + fused IoU-argmax. Block = (anchor tile, b, gt-slice).
// Thread owns one anchor; loops gts staged in LDS (raw boxes; mask flag packed
// into label). Per-pair:
//   - running packed key (iou_bits<<32 | ~g) -> one 64-bit atomicMax per slice
//     == jnp.argmax(ious, axis=1) first-max semantics (iou >= 0).
//   - metric m = score * iou^6 gated by !masked && dmin>eps; positives pushed
//     into per-(b,g) key lists (key = m_bits<<32 | ~l).
// Also zeroes maskbits rows (z==0 blocks).
// ---------------------------------------------------------------------------
__global__ __launch_bounds__(256) void k_scan(
        const float* __restrict__ pred_scores,
        const float4* __restrict__ pred_bboxes,
        const float2* __restrict__ anchor_points,
        const int* __restrict__ gt_labels,
        const float4* __restrict__ gt_bboxes,
        const float* __restrict__ pad_gt_mask,
        uint64_t* __restrict__ keys,
        uint32_t* __restrict__ cnt,
        uint32_t* __restrict__ maskbits,
        unsigned long long* __restrict__ iou_key,
        int B, int L, int C, int n, int W) {
    int b = blockIdx.y;
    int l0 = blockIdx.x * 256;
    int per = (n + GSPLIT - 1) / GSPLIT;
    int gbeg = blockIdx.z * per;
    int gend = min(n, gbeg + per);
    int ng = gend - gbeg;

    extern __shared__ char smem[];
    float4* sbox = (float4*)smem;          // RAW gt boxes (argmax uses unmasked)
    int*    slab = (int*)(sbox + per);     // label | MASKED_FLAG

    for (int i = threadIdx.x; i < ng; i += 256) {
        int g = gbeg + i;
        sbox[i] = gt_bboxes[(size_t)b * n + g];
        int lm = gt_labels[(size_t)b * n + g];
        if (pad_gt_mask[(size_t)b * n + g] == 0.0f) lm |= MASKED_FLAG;
        slab[i] = lm;
    }
    if (blockIdx.z == 0) {  // zero maskbits rows for this (b, tile)
        int rows = min(256, L - l0);
        uint32_t* mb = maskbits + ((size_t)b * L + l0) * W;
        for (int w = threadIdx.x; w < rows * W; w += 256) mb[w] = 0;
    }
    __syncthreads();

    int l = l0 + threadIdx.x;
    if (l >= L) return;
    float2 a = anchor_points[l];
    float4 p = pred_bboxes[(size_t)b * L + l];
    float ap = (p.z - p.x) * (p.w - p.y);
    const float* ps = pred_scores + ((size_t)b * L + l) * C;

    unsigned long long bestkey = 0ull;
    for (int i = 0; i < ng; ++i) {
        float4 gb = sbox[i];
        // IoU for every pair (needed for argmax; reference uses raw boxes)
        float iw = fmaxf(fminf(gb.z, p.z) - fmaxf(gb.x, p.x), 0.0f);
        float ih = fmaxf(fminf(gb.w, p.w) - fmaxf(gb.y, p.y), 0.0f);
        float inter = iw * ih;
        float ag = (gb.z - gb.x) * (gb.w - gb.y);
        float iou = inter / (((ag + ap) - inter) + 1e-9f);
        int g = gbeg + i;
        unsigned long long akey =
            ((unsigned long long)__float_as_uint(iou) << 32) | (uint32_t)(~g);
        if (akey > bestkey) bestkey = akey;   // iou desc, then lowest g

        int lm = slab[i];
        if (!(lm & MASKED_FLAG) && inter > 0.0f) {
            float dmin = fminf(fminf(a.x - gb.x, a.y - gb.y),
                               fminf(gb.z - a.x, gb.w - a.y));
            if (dmin > FEPS) {
                float m = ps[lm] * powf(iou, 6.0f);
                if (m > 0.0f) {
                    int bg = b * n + g;
                    uint32_t off = atomicAdd(&cnt[bg], 1u);
                    if (off < CAP)
                        keys[(size_t)bg * CAP + off] =
                            ((uint64_t)__float_as_uint(m) << 32) | (uint32_t)(~l);
                }
            }
        }
    }
    atomicMax(&iou_key[(size_t)b * L + l], bestkey);
}

// ---------------------------------------------------------------------------
// Kernel 2: selection. One wave per (b,g), fully register/shfl-based:
//  - p<=CAP: load keys, min(p,13) shfl-max rounds (key desc == value desc,
//    index asc), ballot-based zero-fill of lowest-index zero-metric anchors.
//  - p>CAP: dense per-wave recompute fallback (correctness only).
// Picks set bit g in maskbits iff anchor in-gts.
// ---------------------------------------------------------------------------
__global__ __launch_bounds__(256) void k_select(
        const float* __restrict__ pred_scores,
        const float4* __restrict__ pred_bboxes,
        const float2* __restrict__ anchor_points,
        const int* __restrict__ gt_labels,
        const float4* __restrict__ gt_bboxes,
        const float* __restrict__ pad_gt_mask,
        const uint64_t* __restrict__ keys,
        const uint32_t* __restrict__ cnt,
        uint32_t* __restrict__ maskbits,
        int B, int L, int C, int n, int W) {
    int wid = threadIdx.x >> 6;
    int lane = threadIdx.x & 63;
    int bg = blockIdx.x * 4 + wid;
    if (bg >= B * n) return;
    if (pad_gt_mask[bg] == 0.0f) return;
    int b = bg / n;
    int g = bg - b * n;

    uint32_t p = cnt[bg];
    int mypick = -1;

    if (p <= CAP) {
        uint64_t mykey = (lane < (int)p) ? keys[(size_t)bg * CAP + lane] : 0ull;
        int np = min((int)p, NTOPK);
        for (int k = 0; k < np; ++k) {
            uint64_t mk = mykey;
            for (int s = 1; s < 64; s <<= 1) {
                uint64_t o = __shfl_xor((unsigned long long)mk, s);
                if (o > mk) mk = o;
            }
            if (lane == k) mypick = (int)~(uint32_t)mk;
            if (mykey == mk) mykey = 0ull;  // unique owner (index embedded)
        }
        // zero-fill: lowest-index anchors not among the positive picks
        int fill = np, c = 0;
        while (fill < NTOPK) {
            bool inP = __ballot(lane < np && mypick == c) != 0ull;
            if (!inP) {
                if (lane == fill) mypick = c;
                ++fill;
            }
            ++c;
        }
    } else {
        // dense fallback (not taken for this data): 13 recompute rounds
        float4 gb = gt_bboxes[bg];
        float ag = (gb.z - gb.x) * (gb.w - gb.y);
        const float4* pb = pred_bboxes + (size_t)b * L;
        const float*  ps = pred_scores + ((size_t)b * L) * C + gt_labels[bg];
        for (int k = 0; k < NTOPK; ++k) {
            uint64_t bk = 0;
            for (int l = lane; l < L; l += 64) {
                bool taken = false;
                for (int j = 0; j < k; ++j)
                    taken |= (__shfl(mypick, j) == l);
                if (taken) continue;
                float m = tal_metric(l, gb, ag, pb, ps, anchor_points, C);
                uint64_t key = ((uint64_t)__float_as_uint(m) << 32) | (uint32_t)(~l);
                if (key > bk) bk = key;
            }
            for (int s = 1; s < 64; s <<= 1) {
                uint64_t o = __shfl_xor((unsigned long long)bk, s);
                if (o > bk) bk = o;
            }
            if (lane == k) mypick = (int)~(uint32_t)bk;
        }
    }

    if (lane < NTOPK) {
        int l = mypick;
        float4 gb = gt_bboxes[bg];
        float2 a = anchor_points[l];
        float dmin = fminf(fminf(a.x - gb.x, a.y - gb.y),
                           fminf(gb.z - a.x, gb.w - a.y));
        if (dmin > FEPS) {
            atomicOr(&maskbits[((size_t)b * L + l) * W + (g >> 5)],
                     1u << (g & 31));
        }
    }
}

// ---------------------------------------------------------------------------
// Kernel 3: per (b,l): resolve assignment. Pure streaming -- the sum>1 case
// reads the precomputed iou-argmax (no divergent gt loop, no LDS staging).
// ---------------------------------------------------------------------------
__global__ __launch_bounds__(256) void k_assign(
        const float* __restrict__ pred_scores,
        const float4* __restrict__ pred_bboxes,
        const float4* __restrict__ gt_bboxes,
        const int* __restrict__ gt_labels,
        const uint32_t* __restrict__ maskbits,
        const unsigned long long* __restrict__ iou_key,
        const int* __restrict__ bg_ptr,
        int* __restrict__ assigned_g,
        float* __restrict__ align_val,
        uint32_t* __restrict__ max_m,
        uint32_t* __restrict__ max_i,
        float* __restrict__ out_labels,
        float4* __restrict__ out_bboxes,
        int B, int L, int C, int n, int W) {
    int idx = blockIdx.x * blockDim.x + threadIdx.x;
    if (idx >= B * L) return;
    int b = idx / L;

    int sum = 0, firstg = -1;
    for (int w = 0; w < W; ++w) {
        uint32_t bits = maskbits[(size_t)idx * W + w];
        if (bits && firstg < 0) firstg = w * 32 + __ffs(bits) - 1;
        sum += __popc(bits);
    }

    int g;
    if (sum == 0) g = -1;
    else if (sum == 1) g = firstg;
    else g = (int)~(uint32_t)iou_key[idx];   // precomputed first-max argmax-IoU
    assigned_g[idx] = g;

    float av = 0.0f;
    if (g >= 0) {
        float4 p = pred_bboxes[idx];
        float ap = (p.z - p.x) * (p.w - p.y);
        float4 gb = gt_bboxes[(size_t)b * n + g];
        float iw = fmaxf(fminf(gb.z, p.z) - fmaxf(gb.x, p.x), 0.0f);
        float ih = fmaxf(fminf(gb.w, p.w) - fmaxf(gb.y, p.y), 0.0f);
        float inter = iw * ih;
        float ag = (gb.z - gb.x) * (gb.w - gb.y);
        float iou = inter / (((ag + ap) - inter) + 1e-9f);
        int label = gt_labels[(size_t)b * n + g];
        float score = pred_scores[(size_t)idx * C + label];
        av = score * powf(iou, 6.0f);
        atomicMax(&max_m[(size_t)b * n + g], __float_as_uint(av));
        atomicMax(&max_i[(size_t)b * n + g], __float_as_uint(iou));
        out_labels[idx] = (float)label;
        out_bboxes[idx] = gb;
    } else {
        out_labels[idx] = (float)(*bg_ptr);
        out_bboxes[idx] = gt_bboxes[(size_t)b * n];  // agi==0 gather, unmasked
    }
    align_val[idx] = av;
}

// ---------------------------------------------------------------------------
// Kernel 4: scores, float4-vectorized (C % 4 == 0 path).
// ---------------------------------------------------------------------------
__global__ __launch_bounds__(256) void k_scores4(
        const int* __restrict__ assigned_g,
        const float* __restrict__ align_val,
        const uint32_t* __restrict__ max_m,
        const uint32_t* __restrict__ max_i,
        const int* __restrict__ gt_labels,
        const int* __restrict__ bg_ptr,
        float4* __restrict__ out_scores,
        int B, int L, int C, int n, int total4) {
    int idx = blockIdx.x * blockDim.x + threadIdx.x;
    if (idx >= total4) return;
    int C4 = C >> 2;
    int c0 = (idx % C4) * 4;
    int bl = idx / C4;
    int g = assigned_g[bl];
    float4 v = make_float4(0.f, 0.f, 0.f, 0.f);
    if (g >= 0) {
        int b = bl / L;
        int label = gt_labels[(size_t)b * n + g];
        int bgi = *bg_ptr;
        float mm = __uint_as_float(max_m[(size_t)b * n + g]);
        float mi = __uint_as_float(max_i[(size_t)b * n + g]);
        float val = align_val[bl] / (mm + FEPS) * mi;
        int cls0 = (c0     < bgi) ? c0     : c0 + 1;
        int cls1 = (c0 + 1 < bgi) ? c0 + 1 : c0 + 2;
        int cls2 = (c0 + 2 < bgi) ? c0 + 2 : c0 + 3;
        int cls3 = (c0 + 3 < bgi) ? c0 + 3 : c0 + 4;
        if (cls0 == label) v.x = val;
        if (cls1 == label) v.y = val;
        if (cls2 == label) v.z = val;
        if (cls3 == label) v.w = val;
    }
    out_scores[idx] = v;
}

__global__ __launch_bounds__(256) void k_scores1(
        const int* __restrict__ assigned_g,
        const float* __restrict__ align_val,
        const uint32_t* __restrict__ max_m,
        const uint32_t* __restrict__ max_i,
        const int* __restrict__ gt_labels,
        const int* __restrict__ bg_ptr,
        float* __restrict__ out_scores,
        int B, int L, int C, int n, int total) {
    int idx = blockIdx.x * blockDim.x + threadIdx.x;
    if (idx >= total) return;
    int c = idx % C;
    int bl = idx / C;
    int g = assigned_g[bl];
    float v = 0.0f;
    if (g >= 0) {
        int b = bl / L;
        int label = gt_labels[(size_t)b * n + g];
        int bgi = *bg_ptr;
        int cls = (c < bgi) ? c : c + 1;
        if (cls == label) {
            float mm = __uint_as_float(max_m[(size_t)b * n + g]);
            float mi = __uint_as_float(max_i[(size_t)b * n + g]);
            v = align_val[bl] / (mm + FEPS) * mi;
        }
    }
    out_scores[idx] = v;
}

// ---------------------------------------------------------------------------
extern "C" void kernel_launch(void* const* d_in, const int* in_sizes, int n_in,
                              void* d_out, int out_size, void* d_ws, size_t ws_size,
                              hipStream_t stream) {
    const float*  pred_scores   = (const float*)d_in[0];
    const float4* pred_bboxes   = (const float4*)d_in[1];
    const float2* anchor_points = (const float2*)d_in[2];
    const int*    gt_labels     = (const int*)d_in[3];
    const float4* gt_bboxes     = (const float4*)d_in[4];
    const float*  pad_gt_mask   = (const float*)d_in[5];
    const int*    bg_ptr        = (const int*)d_in[6];

    const int L = in_sizes[2] / 2;
    const int B = in_sizes[1] / (L * 4);
    const int C = in_sizes[0] / (B * L);
    const int n = in_sizes[3] / B;
    const int W = (n + 31) / 32;

    // zero-initialized region first (single memset): iou_key, cnt, max_m, max_i
    char* ws = (char*)d_ws;
    unsigned long long* iou_key = (unsigned long long*)ws;
    ws += (size_t)B * L * sizeof(unsigned long long);
    uint32_t* cnt      = (uint32_t*)ws;  ws += (size_t)B * n * sizeof(uint32_t);
    uint32_t* max_m    = (uint32_t*)ws;  ws += (size_t)B * n * sizeof(uint32_t);
    uint32_t* max_i    = (uint32_t*)ws;  ws += (size_t)B * n * sizeof(uint32_t);
    size_t zbytes = (size_t)((char*)ws - (char*)d_ws);
    uint64_t* keys     = (uint64_t*)ws;  ws += (size_t)B * n * CAP * sizeof(uint64_t);
    uint32_t* maskbits = (uint32_t*)ws;  ws += (size_t)B * L * W * sizeof(uint32_t);
    int*      assigned_g = (int*)ws;     ws += (size_t)B * L * sizeof(int);
    float*    align_val  = (float*)ws;   ws += (size_t)B * L * sizeof(float);

    float*  out_labels = (float*)d_out;
    float4* out_bboxes = (float4*)((float*)d_out + (size_t)B * L);
    float*  out_scores = (float*)d_out + (size_t)B * L * 5;

    hipMemsetAsync(d_ws, 0, zbytes, stream);

    {
        int per = (n + GSPLIT - 1) / GSPLIT;
        dim3 grid((L + 255) / 256, B, GSPLIT);
        size_t smem = (size_t)per * (sizeof(float4) + sizeof(int));
        k_scan<<<grid, 256, smem, stream>>>(
            pred_scores, pred_bboxes, anchor_points, gt_labels, gt_bboxes,
            pad_gt_mask, keys, cnt, maskbits, iou_key, B, L, C, n, W);
    }
    k_select<<<(B * n + 3) / 4, 256, 0, stream>>>(
        pred_scores, pred_bboxes, anchor_points, gt_labels, gt_bboxes,
        pad_gt_mask, keys, cnt, maskbits, B, L, C, n, W);
    k_assign<<<(B * L + 255) / 256, 256, 0, stream>>>(
        pred_scores, pred_bboxes, gt_bboxes, gt_labels, maskbits, iou_key,
        bg_ptr, assigned_g, align_val, max_m, max_i, out_labels, out_bboxes,
        B, L, C, n, W);
    if ((C & 3) == 0) {
        int total4 = B * L * (C >> 2);
        k_scores4<<<(total4 + 255) / 256, 256, 0, stream>>>(
            assigned_g, align_val, max_m, max_i, gt_labels, bg_ptr,
            (float4*)out_scores, B, L, C, n, total4);
    } else {
        int total = B * L * C;
        k_scores1<<<(total + 255) / 256, 256, 0, stream>>>(
            assigned_g, align_val, max_m, max_i, gt_labels, bg_ptr,
            out_scores, B, L, C, n, total);
    }
}

// Round 7
// 54.728 us; speedup vs baseline: 5.3728x; 1.0080x over previous
//
#include <hip/hip_runtime.h>
#include <cstdint>

#define NTOPK 13
#define FEPS 1e-9f
#define CAP 64          // per-(b,g) positive-key capacity (p ~ 3 here)
#define GSPLIT 4        // gt-dimension split of the scan grid
#define MASKED_FLAG (1 << 30)

// ---------------------------------------------------------------------------
// Kernel 0: zero the small accumulators (cnt, max_m, max_i). Custom kernel --
// the runtime's fillBufferAligned for hipMemsetAsync ran at 27 GB/s / 41 us.
// ---------------------------------------------------------------------------
__global__ __launch_bounds__(256) void k_zero(uint32_t* __restrict__ p, int nwords) {
    int i = blockIdx.x * 256 + threadIdx.x;
    if (i < nwords) p[i] = 0;
}

// ---------------------------------------------------------------------------
// metric[l] for one gt. Identical arithmetic to the reference.
// ---------------------------------------------------------------------------
__device__ __forceinline__ float tal_metric(int l, float4 gb, float ag,
                                            const float4* __restrict__ pb,
                                            const float* __restrict__ ps,
                                            const float2* __restrict__ apt,
                                            int C) {
    float2 a = apt[l];
    float dmin = fminf(fminf(a.x - gb.x, a.y - gb.y),
                       fminf(gb.z - a.x, gb.w - a.y));
    float m = 0.0f;
    if (dmin > FEPS) {
        float4 p = pb[l];
        float iw = fmaxf(fminf(gb.z, p.z) - fmaxf(gb.x, p.x), 0.0f);
        float ih = fmaxf(fminf(gb.w, p.w) - fmaxf(gb.y, p.y), 0.0f);
        float inter = iw * ih;
        float ap2 = (p.z - p.x) * (p.w - p.y);
        float iou = inter / (((ag + ap2) - inter) + 1e-9f);
        m = ps[(size_t)l * C] * powf(iou, 6.0f);
    }
    return m;
}

// ---------------------------------------------------------------------------
// Kernel 1: sparse scan + per-slice IoU-argmax. Block = (anchor tile, b, slice).
// Thread owns one anchor; loops gts staged in LDS (raw boxes; mask flag packed
// into label). Per-pair:
//   - running packed key (iou_bits<<32 | ~g), PLAIN store per slice (no init
//     needed); k_assign max-reduces slices == jnp.argmax first-max semantics.
//   - metric m = score * iou^6 gated by !masked && dmin>eps; positives pushed
//     into per-(b,g) key lists (key = m_bits<<32 | ~l).
// Also zeroes maskbits rows (z==0 blocks).
// ---------------------------------------------------------------------------
__global__ __launch_bounds__(256) void k_scan(
        const float* __restrict__ pred_scores,
        const float4* __restrict__ pred_bboxes,
        const float2* __restrict__ anchor_points,
        const int* __restrict__ gt_labels,
        const float4* __restrict__ gt_bboxes,
        const float* __restrict__ pad_gt_mask,
        uint64_t* __restrict__ keys,
        uint32_t* __restrict__ cnt,
        uint32_t* __restrict__ maskbits,
        unsigned long long* __restrict__ iou_part,   // [GSPLIT][B*L]
        int B, int L, int C, int n, int W) {
    int b = blockIdx.y;
    int l0 = blockIdx.x * 256;
    int per = (n + GSPLIT - 1) / GSPLIT;
    int gbeg = min(n, (int)blockIdx.z * per);
    int gend = min(n, gbeg + per);
    int ng = gend - gbeg;

    extern __shared__ char smem[];
    float4* sbox = (float4*)smem;          // RAW gt boxes (argmax uses unmasked)
    int*    slab = (int*)(sbox + per);     // label | MASKED_FLAG

    for (int i = threadIdx.x; i < ng; i += 256) {
        int g = gbeg + i;
        sbox[i] = gt_bboxes[(size_t)b * n + g];
        int lm = gt_labels[(size_t)b * n + g];
        if (pad_gt_mask[(size_t)b * n + g] == 0.0f) lm |= MASKED_FLAG;
        slab[i] = lm;
    }
    if (blockIdx.z == 0) {  // zero maskbits rows for this (b, tile)
        int rows = min(256, L - l0);
        uint32_t* mb = maskbits + ((size_t)b * L + l0) * W;
        for (int w = threadIdx.x; w < rows * W; w += 256) mb[w] = 0;
    }
    __syncthreads();

    int l = l0 + threadIdx.x;
    if (l >= L) return;
    float2 a = anchor_points[l];
    float4 p = pred_bboxes[(size_t)b * L + l];
    float ap = (p.z - p.x) * (p.w - p.y);
    const float* ps = pred_scores + ((size_t)b * L + l) * C;

    unsigned long long bestkey = 0ull;
    for (int i = 0; i < ng; ++i) {
        float4 gb = sbox[i];
        // IoU for every pair (needed for argmax; reference uses raw boxes)
        float iw = fmaxf(fminf(gb.z, p.z) - fmaxf(gb.x, p.x), 0.0f);
        float ih = fmaxf(fminf(gb.w, p.w) - fmaxf(gb.y, p.y), 0.0f);
        float inter = iw * ih;
        float ag = (gb.z - gb.x) * (gb.w - gb.y);
        float iou = inter / (((ag + ap) - inter) + 1e-9f);
        int g = gbeg + i;
        unsigned long long akey =
            ((unsigned long long)__float_as_uint(iou) << 32) | (uint32_t)(~g);
        if (akey > bestkey) bestkey = akey;   // iou desc, then lowest g

        int lm = slab[i];
        if (!(lm & MASKED_FLAG) && inter > 0.0f) {
            float dmin = fminf(fminf(a.x - gb.x, a.y - gb.y),
                               fminf(gb.z - a.x, gb.w - a.y));
            if (dmin > FEPS) {
                float m = ps[lm] * powf(iou, 6.0f);
                if (m > 0.0f) {
                    int bg = b * n + g;
                    uint32_t off = atomicAdd(&cnt[bg], 1u);
                    if (off < CAP)
                        keys[(size_t)bg * CAP + off] =
                            ((uint64_t)__float_as_uint(m) << 32) | (uint32_t)(~l);
                }
            }
        }
    }
    iou_part[(size_t)blockIdx.z * B * L + (size_t)b * L + l] = bestkey;
}

// ---------------------------------------------------------------------------
// Kernel 2: selection. One wave per (b,g), fully register/shfl-based:
//  - p<=CAP: load keys, min(p,13) shfl-max rounds (key desc == value desc,
//    index asc), ballot-based zero-fill of lowest-index zero-metric anchors.
//  - p>CAP: dense per-wave recompute fallback (correctness only).
// Picks set bit g in maskbits iff anchor in-gts.
// ---------------------------------------------------------------------------
__global__ __launch_bounds__(256) void k_select(
        const float* __restrict__ pred_scores,
        const float4* __restrict__ pred_bboxes,
        const float2* __restrict__ anchor_points,
        const int* __restrict__ gt_labels,
        const float4* __restrict__ gt_bboxes,
        const float* __restrict__ pad_gt_mask,
        const uint64_t* __restrict__ keys,
        const uint32_t* __restrict__ cnt,
        uint32_t* __restrict__ maskbits,
        int B, int L, int C, int n, int W) {
    int wid = threadIdx.x >> 6;
    int lane = threadIdx.x & 63;
    int bg = blockIdx.x * 4 + wid;
    if (bg >= B * n) return;
    if (pad_gt_mask[bg] == 0.0f) return;
    int b = bg / n;
    int g = bg - b * n;

    uint32_t p = cnt[bg];
    int mypick = -1;

    if (p <= CAP) {
        uint64_t mykey = (lane < (int)p) ? keys[(size_t)bg * CAP + lane] : 0ull;
        int np = min((int)p, NTOPK);
        for (int k = 0; k < np; ++k) {
            uint64_t mk = mykey;
            for (int s = 1; s < 64; s <<= 1) {
                uint64_t o = __shfl_xor((unsigned long long)mk, s);
                if (o > mk) mk = o;
            }
            if (lane == k) mypick = (int)~(uint32_t)mk;
            if (mykey == mk) mykey = 0ull;  // unique owner (index embedded)
        }
        // zero-fill: lowest-index anchors not among the positive picks
        int fill = np, c = 0;
        while (fill < NTOPK) {
            bool inP = __ballot(lane < np && mypick == c) != 0ull;
            if (!inP) {
                if (lane == fill) mypick = c;
                ++fill;
            }
            ++c;
        }
    } else {
        // dense fallback (not taken for this data): 13 recompute rounds
        float4 gb = gt_bboxes[bg];
        float ag = (gb.z - gb.x) * (gb.w - gb.y);
        const float4* pb = pred_bboxes + (size_t)b * L;
        const float*  ps = pred_scores + ((size_t)b * L) * C + gt_labels[bg];
        for (int k = 0; k < NTOPK; ++k) {
            uint64_t bk = 0;
            for (int l = lane; l < L; l += 64) {
                bool taken = false;
                for (int j = 0; j < k; ++j)
                    taken |= (__shfl(mypick, j) == l);
                if (taken) continue;
                float m = tal_metric(l, gb, ag, pb, ps, anchor_points, C);
                uint64_t key = ((uint64_t)__float_as_uint(m) << 32) | (uint32_t)(~l);
                if (key > bk) bk = key;
            }
            for (int s = 1; s < 64; s <<= 1) {
                uint64_t o = __shfl_xor((unsigned long long)bk, s);
                if (o > bk) bk = o;
            }
            if (lane == k) mypick = (int)~(uint32_t)bk;
        }
    }

    if (lane < NTOPK) {
        int l = mypick;
        float4 gb = gt_bboxes[bg];
        float2 a = anchor_points[l];
        float dmin = fminf(fminf(a.x - gb.x, a.y - gb.y),
                           fminf(gb.z - a.x, gb.w - a.y));
        if (dmin > FEPS) {
            atomicOr(&maskbits[((size_t)b * L + l) * W + (g >> 5)],
                     1u << (g & 31));
        }
    }
}

// ---------------------------------------------------------------------------
// Kernel 3: per (b,l): resolve assignment. Pure streaming -- the sum>1 case
// max-reduces the GSPLIT precomputed argmax slices (no divergent gt loop).
// ---------------------------------------------------------------------------
__global__ __launch_bounds__(256) void k_assign(
        const float* __restrict__ pred_scores,
        const float4* __restrict__ pred_bboxes,
        const float4* __restrict__ gt_bboxes,
        const int* __restrict__ gt_labels,
        const uint32_t* __restrict__ maskbits,
        const unsigned long long* __restrict__ iou_part,
        const int* __restrict__ bg_ptr,
        int* __restrict__ assigned_g,
        float* __restrict__ align_val,
        uint32_t* __restrict__ max_m,
        uint32_t* __restrict__ max_i,
        float* __restrict__ out_labels,
        float4* __restrict__ out_bboxes,
        int B, int L, int C, int n, int W) {
    int idx = blockIdx.x * blockDim.x + threadIdx.x;
    if (idx >= B * L) return;
    int b = idx / L;

    int sum = 0, firstg = -1;
    for (int w = 0; w < W; ++w) {
        uint32_t bits = maskbits[(size_t)idx * W + w];
        if (bits && firstg < 0) firstg = w * 32 + __ffs(bits) - 1;
        sum += __popc(bits);
    }

    int g;
    if (sum == 0) g = -1;
    else if (sum == 1) g = firstg;
    else {
        size_t BL = (size_t)B * L;
        unsigned long long bk = iou_part[idx];
        for (int z = 1; z < GSPLIT; ++z) {
            unsigned long long o = iou_part[(size_t)z * BL + idx];
            if (o > bk) bk = o;
        }
        g = (int)~(uint32_t)bk;   // first-max argmax-IoU over all gts
    }
    assigned_g[idx] = g;

    float av = 0.0f;
    if (g >= 0) {
        float4 p = pred_bboxes[idx];
        float ap = (p.z - p.x) * (p.w - p.y);
        float4 gb = gt_bboxes[(size_t)b * n + g];
        float iw = fmaxf(fminf(gb.z, p.z) - fmaxf(gb.x, p.x), 0.0f);
        float ih = fmaxf(fminf(gb.w, p.w) - fmaxf(gb.y, p.y), 0.0f);
        float inter = iw * ih;
        float ag = (gb.z - gb.x) * (gb.w - gb.y);
        float iou = inter / (((ag + ap) - inter) + 1e-9f);
        int label = gt_labels[(size_t)b * n + g];
        float score = pred_scores[(size_t)idx * C + label];
        av = score * powf(iou, 6.0f);
        atomicMax(&max_m[(size_t)b * n + g], __float_as_uint(av));
        atomicMax(&max_i[(size_t)b * n + g], __float_as_uint(iou));
        out_labels[idx] = (float)label;
        out_bboxes[idx] = gb;
    } else {
        out_labels[idx] = (float)(*bg_ptr);
        out_bboxes[idx] = gt_bboxes[(size_t)b * n];  // agi==0 gather, unmasked
    }
    align_val[idx] = av;
}

// ---------------------------------------------------------------------------
// Kernel 4: scores, float4-vectorized (C % 4 == 0 path).
// ---------------------------------------------------------------------------
__global__ __launch_bounds__(256) void k_scores4(
        const int* __restrict__ assigned_g,
        const float* __restrict__ align_val,
        const uint32_t* __restrict__ max_m,
        const uint32_t* __restrict__ max_i,
        const int* __restrict__ gt_labels,
        const int* __restrict__ bg_ptr,
        float4* __restrict__ out_scores,
        int B, int L, int C, int n, int total4) {
    int idx = blockIdx.x * blockDim.x + threadIdx.x;
    if (idx >= total4) return;
    int C4 = C >> 2;
    int c0 = (idx % C4) * 4;
    int bl = idx / C4;
    int g = assigned_g[bl];
    float4 v = make_float4(0.f, 0.f, 0.f, 0.f);
    if (g >= 0) {
        int b = bl / L;
        int label = gt_labels[(size_t)b * n + g];
        int bgi = *bg_ptr;
        float mm = __uint_as_float(max_m[(size_t)b * n + g]);
        float mi = __uint_as_float(max_i[(size_t)b * n + g]);
        float val = align_val[bl] / (mm + FEPS) * mi;
        int cls0 = (c0     < bgi) ? c0     : c0 + 1;
        int cls1 = (c0 + 1 < bgi) ? c0 + 1 : c0 + 2;
        int cls2 = (c0 + 2 < bgi) ? c0 + 2 : c0 + 3;
        int cls3 = (c0 + 3 < bgi) ? c0 + 3 : c0 + 4;
        if (cls0 == label) v.x = val;
        if (cls1 == label) v.y = val;
        if (cls2 == label) v.z = val;
        if (cls3 == label) v.w = val;
    }
    out_scores[idx] = v;
}

__global__ __launch_bounds__(256) void k_scores1(
        const int* __restrict__ assigned_g,
        const float* __restrict__ align_val,
        const uint32_t* __restrict__ max_m,
        const uint32_t* __restrict__ max_i,
        const int* __restrict__ gt_labels,
        const int* __restrict__ bg_ptr,
        float* __restrict__ out_scores,
        int B, int L, int C, int n, int total) {
    int idx = blockIdx.x * blockDim.x + threadIdx.x;
    if (idx >= total) return;
    int c = idx % C;
    int bl = idx / C;
    int g = assigned_g[bl];
    float v = 0.0f;
    if (g >= 0) {
        int b = bl / L;
        int label = gt_labels[(size_t)b * n + g];
        int bgi = *bg_ptr;
        int cls = (c < bgi) ? c : c + 1;
        if (cls == label) {
            float mm = __uint_as_float(max_m[(size_t)b * n + g]);
            float mi = __uint_as_float(max_i[(size_t)b * n + g]);
            v = align_val[bl] / (mm + FEPS) * mi;
        }
    }
    out_scores[idx] = v;
}

// ---------------------------------------------------------------------------
extern "C" void kernel_launch(void* const* d_in, const int* in_sizes, int n_in,
                              void* d_out, int out_size, void* d_ws, size_t ws_size,
                              hipStream_t stream) {
    const float*  pred_scores   = (const float*)d_in[0];
    const float4* pred_bboxes   = (const float4*)d_in[1];
    const float2* anchor_points = (const float2*)d_in[2];
    const int*    gt_labels     = (const int*)d_in[3];
    const float4* gt_bboxes     = (const float4*)d_in[4];
    const float*  pad_gt_mask   = (const float*)d_in[5];
    const int*    bg_ptr        = (const int*)d_in[6];

    const int L = in_sizes[2] / 2;
    const int B = in_sizes[1] / (L * 4);
    const int C = in_sizes[0] / (B * L);
    const int n = in_sizes[3] / B;
    const int W = (n + 31) / 32;

    // small zero region first: cnt, max_m, max_i (zeroed by k_zero)
    char* ws = (char*)d_ws;
    uint32_t* cnt      = (uint32_t*)ws;  ws += (size_t)B * n * sizeof(uint32_t);
    uint32_t* max_m    = (uint32_t*)ws;  ws += (size_t)B * n * sizeof(uint32_t);
    uint32_t* max_i    = (uint32_t*)ws;  ws += (size_t)B * n * sizeof(uint32_t);
    int zwords = 3 * B * n;
    unsigned long long* iou_part = (unsigned long long*)ws;
    ws += (size_t)GSPLIT * B * L * sizeof(unsigned long long);
    uint64_t* keys     = (uint64_t*)ws;  ws += (size_t)B * n * CAP * sizeof(uint64_t);
    uint32_t* maskbits = (uint32_t*)ws;  ws += (size_t)B * L * W * sizeof(uint32_t);
    int*      assigned_g = (int*)ws;     ws += (size_t)B * L * sizeof(int);
    float*    align_val  = (float*)ws;   ws += (size_t)B * L * sizeof(float);

    float*  out_labels = (float*)d_out;
    float4* out_bboxes = (float4*)((float*)d_out + (size_t)B * L);
    float*  out_scores = (float*)d_out + (size_t)B * L * 5;

    k_zero<<<(zwords + 255) / 256, 256, 0, stream>>>((uint32_t*)d_ws, zwords);

    {
        int per = (n + GSPLIT - 1) / GSPLIT;
        dim3 grid((L + 255) / 256, B, GSPLIT);
        size_t smem = (size_t)per * (sizeof(float4) + sizeof(int));
        k_scan<<<grid, 256, smem, stream>>>(
            pred_scores, pred_bboxes, anchor_points, gt_labels, gt_bboxes,
            pad_gt_mask, keys, cnt, maskbits, iou_part, B, L, C, n, W);
    }
    k_select<<<(B * n + 3) / 4, 256, 0, stream>>>(
        pred_scores, pred_bboxes, anchor_points, gt_labels, gt_bboxes,
        pad_gt_mask, keys, cnt, maskbits, B, L, C, n, W);
    k_assign<<<(B * L + 255) / 256, 256, 0, stream>>>(
        pred_scores, pred_bboxes, gt_bboxes, gt_labels, maskbits, iou_part,
        bg_ptr, assigned_g, align_val, max_m, max_i, out_labels, out_bboxes,
        B, L, C, n, W);
    if ((C & 3) == 0) {
        int total4 = B * L * (C >> 2);
        k_scores4<<<(total4 + 255) / 256, 256, 0, stream>>>(
            assigned_g, align_val, max_m, max_i, gt_labels, bg_ptr,
            (float4*)out_scores, B, L, C, n, total4);
    } else {
        int total = B * L * C;
        k_scores1<<<(total + 255) / 256, 256, 0, stream>>>(
            assigned_g, align_val, max_m, max_i, gt_labels, bg_ptr,
            out_scores, B, L, C, n, total);
    }
}